// Round 16
// baseline (1230.374 us; speedup 1.0000x reference)
//
#include <hip/hip_runtime.h>
#include <hip/hip_bf16.h>

#define B_ 16
#define S_ 2048
#define H_ 1024
#define U_ 512
#define NH 8
#define TOPK 100

#define M_ (B_*S_)      // 32768 rows (b,s)
#define NC (NH*U_)      // 4096 cols (n,u)

typedef int i32x4 __attribute__((ext_vector_type(4)));

__device__ __forceinline__ float fast_tanh(float x) {
    float e = __expf(2.f * x);
    return (e - 1.f) / (e + 1.f);
}

__device__ __forceinline__ void gl16i(const signed char* g, signed char* l) {
    __builtin_amdgcn_global_load_lds(
        (const __attribute__((address_space(1))) void*)g,
        (__attribute__((address_space(3))) void*)l, 16, 0, 0);
}

// ---------------- prep: int8 quantization (single-level A and B) ----------------
__global__ void cvtA(const float* __restrict__ v,
                     signed char* __restrict__ h8,
                     float* __restrict__ sa) {
    int row = blockIdx.x * 4 + (threadIdx.x >> 6);
    int l = threadIdx.x & 63;
    const float4* r4 = (const float4*)(v + (size_t)row * 1024);
    float4 x[4];
    float mx = 0.f;
    #pragma unroll
    for (int c = 0; c < 4; ++c) {
        x[c] = r4[l * 4 + c];
        mx = fmaxf(mx, fmaxf(fmaxf(fabsf(x[c].x), fabsf(x[c].y)),
                             fmaxf(fabsf(x[c].z), fabsf(x[c].w))));
    }
    #pragma unroll
    for (int d = 1; d < 64; d <<= 1) mx = fmaxf(mx, __shfl_xor(mx, d));
    float inv = 127.f / mx;
    int wh[4];
    #pragma unroll
    for (int c = 0; c < 4; ++c) {
        float xs[4] = {x[c].x, x[c].y, x[c].z, x[c].w};
        unsigned ph = 0;
        #pragma unroll
        for (int j = 0; j < 4; ++j) {
            float hf = rintf(xs[j] * inv);
            ph |= ((unsigned)((int)hf) & 0xffu) << (8 * j);
        }
        wh[c] = (int)ph;
    }
    *(int4*)(h8 + (size_t)row * 1024 + l * 16) = make_int4(wh[0], wh[1], wh[2], wh[3]);
    if (l == 0) sa[row] = mx / 127.f;
}

// ---- coalesced per-column max of |W1| via atomicMax on uint (cm pre-zeroed) ----
__global__ void colmax_kernel(const float* __restrict__ W1, float* __restrict__ cm) {
    int n = blockIdx.x, h0 = blockIdx.y * 64, u = threadIdx.x;  // 512 threads
    const float* p = W1 + ((size_t)n * H_ + h0) * U_ + u;
    float mx = 0.f;
    #pragma unroll 8
    for (int h = 0; h < 64; ++h) mx = fmaxf(mx, fabsf(p[(size_t)h * U_]));
    atomicMax((unsigned*)(cm + n * U_ + u), __float_as_uint(mx));
}

// W1 [n][h][u] -> BT int8 [n][u][h] (transposed, K=h contiguous; inline inv-scale)
__global__ void cvtB8(const float* __restrict__ W1,
                      const float* __restrict__ cm,
                      signed char* __restrict__ bh) {
    __shared__ float t[64][65];
    int n = blockIdx.x, h0 = blockIdx.y * 64, u0 = blockIdx.z * 64;
    int tid = threadIdx.x;
    int ul = tid & 63;
    #pragma unroll
    for (int i = 0; i < 16; ++i) {
        int hl = i * 4 + (tid >> 6);
        t[hl][ul] = W1[((size_t)n * H_ + h0 + hl) * U_ + u0 + ul];
    }
    __syncthreads();
    #pragma unroll
    for (int i = 0; i < 16; ++i) {
        int ulw = i * 4 + (tid >> 6);
        int hlw = tid & 63;
        float q = t[hlw][ulw] * (127.f / cm[n * 512 + u0 + ulw]);
        size_t o = ((size_t)(n * 512 + u0 + ulw)) * 1024 + h0 + hlw;
        bh[o] = (signed char)(int)rintf(q);
    }
}

// qb partials over 64-h chunks: reads W2 EXACTLY ONCE (16 MB), deterministic
__global__ void qbp_kernel(const float* __restrict__ query,
                           const float* __restrict__ W2,
                           float* __restrict__ qbp) {
    int n = blockIdx.x, hc = blockIdx.y;
    int u = threadIdx.x;            // 512
    int h0 = hc * 64;
    __shared__ float q[16][64];
    #pragma unroll
    for (int k = 0; k < 2; ++k) {
        int idx = threadIdx.x + k * 512;
        q[idx >> 6][idx & 63] = query[(idx >> 6) * H_ + h0 + (idx & 63)];
    }
    __syncthreads();
    float acc[16];
    #pragma unroll
    for (int b = 0; b < 16; ++b) acc[b] = 0.f;
    const float* w2 = W2 + ((size_t)n * H_ + h0) * U_ + u;
    #pragma unroll 4
    for (int hh = 0; hh < 64; ++hh) {
        float wv = w2[(size_t)hh * U_];
        #pragma unroll
        for (int b = 0; b < 16; ++b) acc[b] = fmaf(q[b][hh], wv, acc[b]);
    }
    float* dst = qbp + ((size_t)hc * NH + n) * 16 * U_ + u;
    #pragma unroll
    for (int b = 0; b < 16; ++b) dst[(size_t)b * U_] = acc[b];
}

// qb[n,b,u] = sum_hc qbp + b1 + b2   (fixed-order, deterministic)
__global__ void qb_reduce(const float* __restrict__ qbp,
                          const float* __restrict__ b1,
                          const float* __restrict__ b2,
                          float* __restrict__ qb) {
    int i = blockIdx.x * 256 + threadIdx.x;   // 65536 total
    int n = i >> 13;
    int u = i & 511;
    float s = b1[n * U_ + u] + b2[n * U_ + u];
    #pragma unroll
    for (int hc = 0; hc < 16; ++hc) s += qbp[(size_t)hc * 65536 + i];
    qb[i] = s;
}

// ---------------- main GEMM: single-pass int8, K=1024 (16 tiles of 64) ----------------
// C = sa*(cm/127)*(Ah . B). BM=BN=256, 8 waves.
// NEW: 2-slot ring (64 KB LDS) -> TWO blocks per CU. Block A's fixed costs
// (prologue drain, tanh epilogue, per-tile drains) overlap block B's MFMA
// phase via independent barrier domains (m114 mechanism). Hazards (2-slot,
// prefetch-1, hand-walked): stage(t+1)->slot (t+1)&1 whose iter-(t-1) readers
// drained at end-of-(t-1) lgkmcnt(0)+barrier; reads(t+1) follow end-of-t
// vmcnt(0)+barrier. One barrier per tile.
#define NT 16
#define SWZ(d) ((d) ^ ((((d) >> 7) & 3) << 4))
#define K0B(tt) ((tt) * 64)
#define STAGE_A(tt, j) gl16i(Ah8 + (size_t)(rowBase + (j)*128 + rT) * 1024 + K0B(tt) + cTb, \
                             lds + ((tt)&1)*32768 + (j)*8192 + tid*16)
#define STAGE_B(tt, j) gl16i(Bh8 + (size_t)(colBase + (j)*128 + rT) * 1024 + K0B(tt) + cTb, \
                             lds + ((tt)&1)*32768 + 16384 + (j)*8192 + tid*16)

__global__ __launch_bounds__(512, 4) void gemm8i(
        const signed char* __restrict__ Ah8,
        const signed char* __restrict__ Bh8,
        const float* __restrict__ sa, const float* __restrict__ cm,
        const float* __restrict__ qb, const float* __restrict__ Vw,
        const float* __restrict__ Ww, float* __restrict__ partial) {
    __shared__ signed char lds[65536];   // 2 slots x (A 16KB | B 16KB)
    const int tid = threadIdx.x;
    const int lane = tid & 63;
    const int wid = tid >> 6;
    const int wm = wid >> 2, wn = wid & 3;   // 2 x 4 wave grid
    int bid = blockIdx.x;
    int swz = (bid & 7) * 256 + (bid >> 3);  // XCD swizzle (2048 % 8 == 0)
    int mIdx = swz & 127, nIdx = swz >> 7;
    int rowBase = mIdx * 256, colBase = nIdx * 256;

    // staging decode: linear LDS dst -> swizzled global src (8KB chunk)
    int d0 = tid * 16;
    int d0s = SWZ(d0);
    int rT  = d0s >> 6;       // row 0..127 within chunk
    int cTb = d0s & 63;       // byte col within 64B row

    // fragment ds_read byte offsets (swizzled, slot-relative)
    const int l15 = lane & 15, l4 = lane >> 4;
    int offA[8], offB[4];
    #pragma unroll
    for (int m = 0; m < 8; ++m)
        offA[m] = SWZ((wm * 128 + m * 16 + l15) * 64 + l4 * 16);
    #pragma unroll
    for (int n = 0; n < 4; ++n)
        offB[n] = 16384 + SWZ((wn * 64 + n * 16 + l15) * 64 + l4 * 16);

    i32x4 acc[8][4];
    #pragma unroll
    for (int m = 0; m < 8; ++m)
        #pragma unroll
        for (int n = 0; n < 4; ++n) acc[m][n] = (i32x4){0, 0, 0, 0};

    // prologue: stage tile 0, drain, barrier
    STAGE_A(0, 0); STAGE_A(0, 1); STAGE_B(0, 0); STAGE_B(0, 1);
    asm volatile("s_waitcnt vmcnt(0)" ::: "memory");
    __builtin_amdgcn_s_barrier();

    #pragma unroll 1
    for (int t = 0; t < NT; ++t) {
        __builtin_amdgcn_sched_barrier(0);
        // issue next-tile staging first (long-latency VMEM)
        if (t + 1 < NT) {
            STAGE_A(t + 1, 0); STAGE_A(t + 1, 1);
            STAGE_B(t + 1, 0); STAGE_B(t + 1, 1);
        }
        // reads + MFMA unpinned: compiler interleaves with counted lgkmcnt
        const signed char* slot = lds + (t & 1) * 32768;
        i32x4 bf[4], af[8];
        #pragma unroll
        for (int n = 0; n < 4; ++n) bf[n] = *(const i32x4*)(slot + offB[n]);
        #pragma unroll
        for (int m = 0; m < 8; ++m) af[m] = *(const i32x4*)(slot + offA[m]);
        #pragma unroll
        for (int m = 0; m < 8; ++m)
            #pragma unroll
            for (int n = 0; n < 4; ++n)
                acc[m][n] = __builtin_amdgcn_mfma_i32_16x16x64_i8(af[m], bf[n], acc[m][n], 0, 0, 0);
        // drain own reads + next-tile staging, then sync
        asm volatile("s_waitcnt lgkmcnt(0)" ::: "memory");
        asm volatile("s_waitcnt vmcnt(0)" ::: "memory");
        __builtin_amdgcn_s_barrier();
    }

    // epilogue: Cf = acc*sa*(cm/127); tanh + Vw*Ww row-reduce; cross-wave LDS reduce
    int hd = colBase >> 9;
    int b = rowBase >> 11;
    float wwn = Ww[hd];
    float qv[4], vw[4], sbv[4];
    #pragma unroll
    for (int n = 0; n < 4; ++n) {
        int col = colBase + wn * 64 + n * 16 + l15;
        int u = col & 511;
        qv[n] = qb[((size_t)hd * B_ + b) * U_ + u];
        vw[n] = Vw[hd * U_ + u] * wwn;
        sbv[n] = cm[col] * (1.f / 127.f);
    }
    float* red = (float*)lds;   // [4 wn][256 rows]
    #pragma unroll
    for (int m = 0; m < 8; ++m) {
        float sav[4];
        #pragma unroll
        for (int r = 0; r < 4; ++r)
            sav[r] = sa[rowBase + wm * 128 + m * 16 + l4 * 4 + r];
        #pragma unroll
        for (int r = 0; r < 4; ++r) {
            float p = 0.f;
            #pragma unroll
            for (int n = 0; n < 4; ++n)
                p += vw[n] * fast_tanh((float)acc[m][n][r] * sav[r] * sbv[n] + qv[n]);
            p += __shfl_xor(p, 1);
            p += __shfl_xor(p, 2);
            p += __shfl_xor(p, 4);
            p += __shfl_xor(p, 8);
            if (l15 == 0)
                red[wn * 256 + wm * 128 + m * 16 + l4 * 4 + r] = p;
        }
    }
    __syncthreads();
    if (tid < 256) {
        float s = red[tid] + red[256 + tid] + red[512 + tid] + red[768 + tid];
        partial[(size_t)nIdx * M_ + rowBase + tid] = s;
    }
}

// ---------------- fallback fp32 GEMM (if ws too small) ----------------
__global__ __launch_bounds__(256, 2) void gemm_score(
        const float* __restrict__ values,
        const float* __restrict__ W1,
        const float* __restrict__ qb,
        const float* __restrict__ Vw,
        const float* __restrict__ Ww,
        float* __restrict__ partial) {
    __shared__ float As[16][128 + 4];
    __shared__ float Bs[16][128 + 4];
    int tid = threadIdx.x;
    int tx = tid & 15, ty = tid >> 4;
    int rowBase = blockIdx.x * 128;
    int colBase = blockIdx.y * 128;
    int n = colBase >> 9;
    int u0 = colBase & 511;
    int b = rowBase >> 11;
    float acc[8][8];
    #pragma unroll
    for (int i = 0; i < 8; ++i)
        #pragma unroll
        for (int j = 0; j < 8; ++j) acc[i][j] = 0.f;
    const float* Ag = values + (size_t)rowBase * H_;
    const float* Bg = W1 + (size_t)n * H_ * U_ + u0;
    for (int k0 = 0; k0 < H_; k0 += 16) {
        #pragma unroll
        for (int r = 0; r < 2; ++r) {
            int idx = tid + r * 256;
            int arow = idx >> 2, aqc = idx & 3;
            float4 v = *(const float4*)(Ag + (size_t)arow * H_ + k0 + aqc * 4);
            As[aqc * 4 + 0][arow] = v.x;
            As[aqc * 4 + 1][arow] = v.y;
            As[aqc * 4 + 2][arow] = v.z;
            As[aqc * 4 + 3][arow] = v.w;
        }
        #pragma unroll
        for (int r = 0; r < 2; ++r) {
            int idx = tid + r * 256;
            int bk = idx >> 5, bqc = idx & 31;
            float4 v = *(const float4*)(Bg + (size_t)(k0 + bk) * U_ + bqc * 4);
            *(float4*)&Bs[bk][bqc * 4] = v;
        }
        __syncthreads();
        #pragma unroll
        for (int k = 0; k < 16; ++k) {
            float4 a0 = *(const float4*)&As[k][ty * 8];
            float4 a1 = *(const float4*)&As[k][ty * 8 + 4];
            float4 b0 = *(const float4*)&Bs[k][tx * 8];
            float4 b1v = *(const float4*)&Bs[k][tx * 8 + 4];
            float av[8] = {a0.x, a0.y, a0.z, a0.w, a1.x, a1.y, a1.z, a1.w};
            float bv[8] = {b0.x, b0.y, b0.z, b0.w, b1v.x, b1v.y, b1v.z, b1v.w};
            #pragma unroll
            for (int i = 0; i < 8; ++i)
                #pragma unroll
                for (int j = 0; j < 8; ++j)
                    acc[i][j] = fmaf(av[i], bv[j], acc[i][j]);
        }
        __syncthreads();
    }
    float qbv[8], vwv[8];
    #pragma unroll
    for (int j = 0; j < 8; ++j) {
        int u = u0 + tx * 8 + j;
        qbv[j] = qb[(n * B_ + b) * U_ + u];
        vwv[j] = Vw[n * U_ + u];
    }
    float wwn = Ww[n];
    #pragma unroll
    for (int i = 0; i < 8; ++i) {
        float p = 0.f;
        #pragma unroll
        for (int j = 0; j < 8; ++j)
            p += vwv[j] * fast_tanh(acc[i][j] + qbv[j]);
        p += __shfl_xor(p, 1);
        p += __shfl_xor(p, 2);
        p += __shfl_xor(p, 4);
        p += __shfl_xor(p, 8);
        if (tx == 0)
            partial[(size_t)blockIdx.y * M_ + rowBase + ty * 8 + i] = wwn * p;
    }
}

// ---------------- tail kernels ----------------
// topk with fused partial-reduction (reads partial directly)
__global__ __launch_bounds__(1024) void topk_kernel(
        const float* __restrict__ partial, int nparts,
        const float* __restrict__ Vb,
        const float* __restrict__ Ww,
        const float* __restrict__ Wb,
        float* __restrict__ out_masked,
        float* __restrict__ w_un) {
    __shared__ float sc[S_];
    __shared__ float srt[S_];
    __shared__ int cnt_gt;
    int b = blockIdx.x;
    int tid = threadIdx.x;
    float cst = Wb[0];
    #pragma unroll
    for (int n2 = 0; n2 < NH; ++n2) cst += Ww[n2] * Vb[n2];
    for (int s = tid; s < S_; s += 1024) {
        float v = cst;
        for (int ct = 0; ct < nparts; ++ct)
            v += partial[(size_t)ct * M_ + b * S_ + s];
        sc[s] = v; srt[s] = v;
    }
    if (tid == 0) cnt_gt = 0;
    __syncthreads();
    for (int k = 2; k <= S_; k <<= 1) {
        for (int j = k >> 1; j >= 1; j >>= 1) {
            int i = ((tid & ~(j - 1)) << 1) | (tid & (j - 1));
            int p = i | j;
            float a = srt[i], c2 = srt[p];
            if (((i & k) == 0) ? (a > c2) : (a < c2)) { srt[i] = c2; srt[p] = a; }
            __syncthreads();
        }
    }
    float T = srt[S_ - TOPK];
    int c = 0;
    for (int s = tid; s < S_; s += 1024) c += (sc[s] > T);
    atomicAdd(&cnt_gt, c);
    __syncthreads();
    int need_eq = TOPK - cnt_gt;
    for (int s = tid; s < S_; s += 1024) {
        float v = sc[s];
        bool sel = (v > T);
        if (v == T) {
            int rank = 0;
            for (int t2 = 0; t2 < s; ++t2) rank += (sc[t2] == T);
            sel = (rank < need_eq);
        }
        float m = sel ? v : 0.f;
        out_masked[b * S_ + s] = m;
        w_un[b * S_ + s] = 1.f / (1.f + __expf(-m));
    }
}

__global__ void norm_w(const float* __restrict__ w_un, float* __restrict__ out_w) {
    int s = blockIdx.x * blockDim.x + threadIdx.x;
    float d = 0.f;
    #pragma unroll
    for (int b = 0; b < B_; ++b) d += w_un[b * S_ + s];
    float inv = 1.f / d;
    #pragma unroll
    for (int b = 0; b < B_; ++b) out_w[b * S_ + s] = w_un[b * S_ + s] * inv;
}

// context partials from 1-level int8 values (v ~= sa*h): 32MB read
__global__ void ctx_partial_h8(const signed char* __restrict__ h8,
                               const float* __restrict__ sa,
                               const float* __restrict__ w,
                               float* __restrict__ pctx) {
    int bb = blockIdx.x;
    int h = blockIdx.y * 256 + threadIdx.x;
    int s0 = blockIdx.z * 256;
    __shared__ float ws[256];
    {
        int s = threadIdx.x;
        ws[s] = w[bb * S_ + s0 + s] * sa[bb * S_ + s0 + s];
    }
    __syncthreads();
    const signed char* hp = h8 + (size_t)(bb * S_ + s0) * H_ + h;
    float acc = 0.f;
    #pragma unroll 4
    for (int s = 0; s < 256; ++s)
        acc += ws[s] * (float)hp[(size_t)s * H_];
    pctx[((size_t)blockIdx.z * B_ + bb) * H_ + h] = acc;
}

__global__ void ctx_partial_f32(const float* __restrict__ values,
                                const float* __restrict__ w,
                                float* __restrict__ pctx) {
    int bb = blockIdx.x;
    int h = blockIdx.y * 256 + threadIdx.x;
    int s0 = blockIdx.z * 256;
    __shared__ float wrow[256];
    wrow[threadIdx.x] = w[bb * S_ + s0 + threadIdx.x];
    __syncthreads();
    const float* vp = values + (size_t)(bb * S_ + s0) * H_ + h;
    float acc = 0.f;
    #pragma unroll 4
    for (int s = 0; s < 256; ++s) acc += wrow[s] * vp[(size_t)s * H_];
    pctx[((size_t)blockIdx.z * B_ + bb) * H_ + h] = acc;
}

__global__ void ctx_reduce(const float* __restrict__ pctx,
                           float* __restrict__ out_ctx) {
    int i = blockIdx.x * blockDim.x + threadIdx.x;
    float s = 0.f;
    #pragma unroll
    for (int z = 0; z < 8; ++z) s += pctx[(size_t)z * B_ * H_ + i];
    out_ctx[i] = s;
}

extern "C" void kernel_launch(void* const* d_in, const int* in_sizes, int n_in,
                              void* d_out, int out_size, void* d_ws, size_t ws_size,
                              hipStream_t stream) {
    const float* query = (const float*)d_in[0];
    const float* values = (const float*)d_in[1];
    const float* W1 = (const float*)d_in[2];
    const float* b1 = (const float*)d_in[3];
    const float* W2 = (const float*)d_in[4];
    const float* b2 = (const float*)d_in[5];
    const float* Vw = (const float*)d_in[6];
    const float* Vb = (const float*)d_in[7];
    const float* Ww = (const float*)d_in[8];
    const float* Wb = (const float*)d_in[9];

    float* ws = (float*)d_ws;
    float* qb      = ws;                     // 65536
    float* qbp     = qb + 65536;             // 1048576 (16 x 65536)
    float* partial = qbp + 1048576;          // 1048576 (32 x 32768)
    float* w_un    = partial + 1048576;      // 32768
    float* pctx    = w_un + 32768;           // 131072
    float* sa      = pctx + 131072;          // 32768
    float* colmax  = sa + 32768;             // 4096
    signed char* Ah8 = (signed char*)(colmax + 4096);  // 32 MB
    signed char* Bh8 = Ah8 + (size_t)M_ * H_;          // 4 MB
    size_t needed = (size_t)((char*)(Bh8 + (size_t)NC * H_) - (char*)d_ws);

    float* out_ctx    = (float*)d_out;       // 16384
    float* out_w      = out_ctx + 16384;     // 32768
    float* out_masked = out_w + 32768;       // 32768

    qbp_kernel<<<dim3(NH, 16), 512, 0, stream>>>(query, W2, qbp);
    qb_reduce<<<dim3(256), 256, 0, stream>>>(qbp, b1, b2, qb);
    if (ws_size >= needed) {
        cvtA<<<dim3(8192), 256, 0, stream>>>(values, Ah8, sa);
        hipMemsetAsync(colmax, 0, NC * sizeof(float), stream);
        colmax_kernel<<<dim3(NH, 16), 512, 0, stream>>>(W1, colmax);
        cvtB8<<<dim3(NH, 16, 8), 256, 0, stream>>>(W1, colmax, Bh8);
        gemm8i<<<dim3(2048), 512, 0, stream>>>(Ah8, Bh8, sa, colmax,
                                               qb, Vw, Ww, partial);
        topk_kernel<<<16, 1024, 0, stream>>>(partial, 16, Vb, Ww, Wb, out_masked, w_un);
        norm_w<<<8, 256, 0, stream>>>(w_un, out_w);
        ctx_partial_h8<<<dim3(16, 4, 8), 256, 0, stream>>>(Ah8, sa, out_w, pctx);
    } else {
        gemm_score<<<dim3(256, 32), 256, 0, stream>>>(values, W1, qb, Vw, Ww, partial);
        topk_kernel<<<16, 1024, 0, stream>>>(partial, 32, Vb, Ww, Wb, out_masked, w_un);
        norm_w<<<8, 256, 0, stream>>>(w_un, out_w);
        ctx_partial_f32<<<dim3(16, 4, 8), 256, 0, stream>>>(values, out_w, pctx);
    }
    ctx_reduce<<<64, 256, 0, stream>>>(pctx, out_ctx);
}

// Round 17
// 394.691 us; speedup vs baseline: 3.1173x; 3.1173x over previous
//
#include <hip/hip_runtime.h>
#include <hip/hip_bf16.h>

#define B_ 16
#define S_ 2048
#define H_ 1024
#define U_ 512
#define NH 8
#define TOPK 100

#define M_ (B_*S_)      // 32768 rows (b,s)
#define NC (NH*U_)      // 4096 cols (n,u)

typedef int i32x4 __attribute__((ext_vector_type(4)));

__device__ __forceinline__ float fast_tanh(float x) {
    float e = __expf(2.f * x);
    return (e - 1.f) / (e + 1.f);
}

__device__ __forceinline__ void gl16i(const signed char* g, signed char* l) {
    __builtin_amdgcn_global_load_lds(
        (const __attribute__((address_space(1))) void*)g,
        (__attribute__((address_space(3))) void*)l, 16, 0, 0);
}

// ---------------- prep: int8 quantization (single-level A and B) ----------------
__global__ void cvtA(const float* __restrict__ v,
                     signed char* __restrict__ h8,
                     float* __restrict__ sa) {
    int row = blockIdx.x * 4 + (threadIdx.x >> 6);
    int l = threadIdx.x & 63;
    const float4* r4 = (const float4*)(v + (size_t)row * 1024);
    float4 x[4];
    float mx = 0.f;
    #pragma unroll
    for (int c = 0; c < 4; ++c) {
        x[c] = r4[l * 4 + c];
        mx = fmaxf(mx, fmaxf(fmaxf(fabsf(x[c].x), fabsf(x[c].y)),
                             fmaxf(fabsf(x[c].z), fabsf(x[c].w))));
    }
    #pragma unroll
    for (int d = 1; d < 64; d <<= 1) mx = fmaxf(mx, __shfl_xor(mx, d));
    float inv = 127.f / mx;
    int wh[4];
    #pragma unroll
    for (int c = 0; c < 4; ++c) {
        float xs[4] = {x[c].x, x[c].y, x[c].z, x[c].w};
        unsigned ph = 0;
        #pragma unroll
        for (int j = 0; j < 4; ++j) {
            float hf = rintf(xs[j] * inv);
            ph |= ((unsigned)((int)hf) & 0xffu) << (8 * j);
        }
        wh[c] = (int)ph;
    }
    *(int4*)(h8 + (size_t)row * 1024 + l * 16) = make_int4(wh[0], wh[1], wh[2], wh[3]);
    if (l == 0) sa[row] = mx / 127.f;
}

// ---- coalesced per-column max of |W1| via atomicMax on uint (cm pre-zeroed) ----
__global__ void colmax_kernel(const float* __restrict__ W1, float* __restrict__ cm) {
    int n = blockIdx.x, h0 = blockIdx.y * 64, u = threadIdx.x;  // 512 threads
    const float* p = W1 + ((size_t)n * H_ + h0) * U_ + u;
    float mx = 0.f;
    #pragma unroll 8
    for (int h = 0; h < 64; ++h) mx = fmaxf(mx, fabsf(p[(size_t)h * U_]));
    atomicMax((unsigned*)(cm + n * U_ + u), __float_as_uint(mx));
}

// W1 [n][h][u] -> BT int8 [n][u][h] (transposed, K=h contiguous; inline inv-scale)
__global__ void cvtB8(const float* __restrict__ W1,
                      const float* __restrict__ cm,
                      signed char* __restrict__ bh) {
    __shared__ float t[64][65];
    int n = blockIdx.x, h0 = blockIdx.y * 64, u0 = blockIdx.z * 64;
    int tid = threadIdx.x;
    int ul = tid & 63;
    #pragma unroll
    for (int i = 0; i < 16; ++i) {
        int hl = i * 4 + (tid >> 6);
        t[hl][ul] = W1[((size_t)n * H_ + h0 + hl) * U_ + u0 + ul];
    }
    __syncthreads();
    #pragma unroll
    for (int i = 0; i < 16; ++i) {
        int ulw = i * 4 + (tid >> 6);
        int hlw = tid & 63;
        float q = t[hlw][ulw] * (127.f / cm[n * 512 + u0 + ulw]);
        size_t o = ((size_t)(n * 512 + u0 + ulw)) * 1024 + h0 + hlw;
        bh[o] = (signed char)(int)rintf(q);
    }
}

// qb partials over 64-h chunks: reads W2 EXACTLY ONCE (16 MB), deterministic
__global__ void qbp_kernel(const float* __restrict__ query,
                           const float* __restrict__ W2,
                           float* __restrict__ qbp) {
    int n = blockIdx.x, hc = blockIdx.y;
    int u = threadIdx.x;            // 512
    int h0 = hc * 64;
    __shared__ float q[16][64];
    #pragma unroll
    for (int k = 0; k < 2; ++k) {
        int idx = threadIdx.x + k * 512;
        q[idx >> 6][idx & 63] = query[(idx >> 6) * H_ + h0 + (idx & 63)];
    }
    __syncthreads();
    float acc[16];
    #pragma unroll
    for (int b = 0; b < 16; ++b) acc[b] = 0.f;
    const float* w2 = W2 + ((size_t)n * H_ + h0) * U_ + u;
    #pragma unroll 4
    for (int hh = 0; hh < 64; ++hh) {
        float wv = w2[(size_t)hh * U_];
        #pragma unroll
        for (int b = 0; b < 16; ++b) acc[b] = fmaf(q[b][hh], wv, acc[b]);
    }
    float* dst = qbp + ((size_t)hc * NH + n) * 16 * U_ + u;
    #pragma unroll
    for (int b = 0; b < 16; ++b) dst[(size_t)b * U_] = acc[b];
}

// qb[n,b,u] = sum_hc qbp + b1 + b2   (fixed-order, deterministic)
__global__ void qb_reduce(const float* __restrict__ qbp,
                          const float* __restrict__ b1,
                          const float* __restrict__ b2,
                          float* __restrict__ qb) {
    int i = blockIdx.x * 256 + threadIdx.x;   // 65536 total
    int n = i >> 13;
    int u = i & 511;
    float s = b1[n * U_ + u] + b2[n * U_ + u];
    #pragma unroll
    for (int hc = 0; hc < 16; ++hc) s += qbp[(size_t)hc * 65536 + i];
    qb[i] = s;
}

// ---------------- main GEMM: single-pass int8, K=1024 (16 tiles of 64) ----------------
// C = sa*(cm/127)*(Ah . B). BM=BN=256, 8 waves.
// 2-slot ring (64 KB LDS) -> TWO blocks per CU (independent barrier domains ->
// cross-block phase overlap, m114). R15 retry with CORRECT launch bound:
// (512,2) caps VGPR at 256 (actual ~100 <= 128 so 2 blocks still fit) -- R15's
// (512,4) forced a 64-VGPR budget and spilled acc to scratch (WRITE 2.8 MB).
#define NT 16
#define SWZ(d) ((d) ^ ((((d) >> 7) & 3) << 4))
#define K0B(tt) ((tt) * 64)
#define STAGE_A(tt, j) gl16i(Ah8 + (size_t)(rowBase + (j)*128 + rT) * 1024 + K0B(tt) + cTb, \
                             lds + ((tt)&1)*32768 + (j)*8192 + tid*16)
#define STAGE_B(tt, j) gl16i(Bh8 + (size_t)(colBase + (j)*128 + rT) * 1024 + K0B(tt) + cTb, \
                             lds + ((tt)&1)*32768 + 16384 + (j)*8192 + tid*16)

__global__ __launch_bounds__(512, 2) void gemm8i(
        const signed char* __restrict__ Ah8,
        const signed char* __restrict__ Bh8,
        const float* __restrict__ sa, const float* __restrict__ cm,
        const float* __restrict__ qb, const float* __restrict__ Vw,
        const float* __restrict__ Ww, float* __restrict__ partial) {
    __shared__ signed char lds[65536];   // 2 slots x (A 16KB | B 16KB)
    const int tid = threadIdx.x;
    const int lane = tid & 63;
    const int wid = tid >> 6;
    const int wm = wid >> 2, wn = wid & 3;   // 2 x 4 wave grid
    int bid = blockIdx.x;
    int swz = (bid & 7) * 256 + (bid >> 3);  // XCD swizzle (2048 % 8 == 0)
    int mIdx = swz & 127, nIdx = swz >> 7;
    int rowBase = mIdx * 256, colBase = nIdx * 256;

    // staging decode: linear LDS dst -> swizzled global src (8KB chunk)
    int d0 = tid * 16;
    int d0s = SWZ(d0);
    int rT  = d0s >> 6;       // row 0..127 within chunk
    int cTb = d0s & 63;       // byte col within 64B row

    // fragment ds_read byte offsets (swizzled, slot-relative)
    const int l15 = lane & 15, l4 = lane >> 4;
    int offA[8], offB[4];
    #pragma unroll
    for (int m = 0; m < 8; ++m)
        offA[m] = SWZ((wm * 128 + m * 16 + l15) * 64 + l4 * 16);
    #pragma unroll
    for (int n = 0; n < 4; ++n)
        offB[n] = 16384 + SWZ((wn * 64 + n * 16 + l15) * 64 + l4 * 16);

    i32x4 acc[8][4];
    #pragma unroll
    for (int m = 0; m < 8; ++m)
        #pragma unroll
        for (int n = 0; n < 4; ++n) acc[m][n] = (i32x4){0, 0, 0, 0};

    // prologue: stage tile 0, drain, barrier
    STAGE_A(0, 0); STAGE_A(0, 1); STAGE_B(0, 0); STAGE_B(0, 1);
    asm volatile("s_waitcnt vmcnt(0)" ::: "memory");
    __builtin_amdgcn_s_barrier();

    #pragma unroll 1
    for (int t = 0; t < NT; ++t) {
        __builtin_amdgcn_sched_barrier(0);
        // issue next-tile staging first (long-latency VMEM)
        if (t + 1 < NT) {
            STAGE_A(t + 1, 0); STAGE_A(t + 1, 1);
            STAGE_B(t + 1, 0); STAGE_B(t + 1, 1);
        }
        // reads + MFMA unpinned: compiler interleaves with counted lgkmcnt
        const signed char* slot = lds + (t & 1) * 32768;
        i32x4 bf[4], af[8];
        #pragma unroll
        for (int n = 0; n < 4; ++n) bf[n] = *(const i32x4*)(slot + offB[n]);
        #pragma unroll
        for (int m = 0; m < 8; ++m) af[m] = *(const i32x4*)(slot + offA[m]);
        #pragma unroll
        for (int m = 0; m < 8; ++m)
            #pragma unroll
            for (int n = 0; n < 4; ++n)
                acc[m][n] = __builtin_amdgcn_mfma_i32_16x16x64_i8(af[m], bf[n], acc[m][n], 0, 0, 0);
        // drain own reads + next-tile staging, then sync
        asm volatile("s_waitcnt lgkmcnt(0)" ::: "memory");
        asm volatile("s_waitcnt vmcnt(0)" ::: "memory");
        __builtin_amdgcn_s_barrier();
    }

    // epilogue: Cf = acc*sa*(cm/127); tanh + Vw*Ww row-reduce; cross-wave LDS reduce
    int hd = colBase >> 9;
    int b = rowBase >> 11;
    float wwn = Ww[hd];
    float qv[4], vw[4], sbv[4];
    #pragma unroll
    for (int n = 0; n < 4; ++n) {
        int col = colBase + wn * 64 + n * 16 + l15;
        int u = col & 511;
        qv[n] = qb[((size_t)hd * B_ + b) * U_ + u];
        vw[n] = Vw[hd * U_ + u] * wwn;
        sbv[n] = cm[col] * (1.f / 127.f);
    }
    float* red = (float*)lds;   // [4 wn][256 rows]
    #pragma unroll
    for (int m = 0; m < 8; ++m) {
        float sav[4];
        #pragma unroll
        for (int r = 0; r < 4; ++r)
            sav[r] = sa[rowBase + wm * 128 + m * 16 + l4 * 4 + r];
        #pragma unroll
        for (int r = 0; r < 4; ++r) {
            float p = 0.f;
            #pragma unroll
            for (int n = 0; n < 4; ++n)
                p += vw[n] * fast_tanh((float)acc[m][n][r] * sav[r] * sbv[n] + qv[n]);
            p += __shfl_xor(p, 1);
            p += __shfl_xor(p, 2);
            p += __shfl_xor(p, 4);
            p += __shfl_xor(p, 8);
            if (l15 == 0)
                red[wn * 256 + wm * 128 + m * 16 + l4 * 4 + r] = p;
        }
    }
    __syncthreads();
    if (tid < 256) {
        float s = red[tid] + red[256 + tid] + red[512 + tid] + red[768 + tid];
        partial[(size_t)nIdx * M_ + rowBase + tid] = s;
    }
}

// ---------------- fallback fp32 GEMM (if ws too small) ----------------
__global__ __launch_bounds__(256, 2) void gemm_score(
        const float* __restrict__ values,
        const float* __restrict__ W1,
        const float* __restrict__ qb,
        const float* __restrict__ Vw,
        const float* __restrict__ Ww,
        float* __restrict__ partial) {
    __shared__ float As[16][128 + 4];
    __shared__ float Bs[16][128 + 4];
    int tid = threadIdx.x;
    int tx = tid & 15, ty = tid >> 4;
    int rowBase = blockIdx.x * 128;
    int colBase = blockIdx.y * 128;
    int n = colBase >> 9;
    int u0 = colBase & 511;
    int b = rowBase >> 11;
    float acc[8][8];
    #pragma unroll
    for (int i = 0; i < 8; ++i)
        #pragma unroll
        for (int j = 0; j < 8; ++j) acc[i][j] = 0.f;
    const float* Ag = values + (size_t)rowBase * H_;
    const float* Bg = W1 + (size_t)n * H_ * U_ + u0;
    for (int k0 = 0; k0 < H_; k0 += 16) {
        #pragma unroll
        for (int r = 0; r < 2; ++r) {
            int idx = tid + r * 256;
            int arow = idx >> 2, aqc = idx & 3;
            float4 v = *(const float4*)(Ag + (size_t)arow * H_ + k0 + aqc * 4);
            As[aqc * 4 + 0][arow] = v.x;
            As[aqc * 4 + 1][arow] = v.y;
            As[aqc * 4 + 2][arow] = v.z;
            As[aqc * 4 + 3][arow] = v.w;
        }
        #pragma unroll
        for (int r = 0; r < 2; ++r) {
            int idx = tid + r * 256;
            int bk = idx >> 5, bqc = idx & 31;
            float4 v = *(const float4*)(Bg + (size_t)(k0 + bk) * U_ + bqc * 4);
            *(float4*)&Bs[bk][bqc * 4] = v;
        }
        __syncthreads();
        #pragma unroll
        for (int k = 0; k < 16; ++k) {
            float4 a0 = *(const float4*)&As[k][ty * 8];
            float4 a1 = *(const float4*)&As[k][ty * 8 + 4];
            float4 b0 = *(const float4*)&Bs[k][tx * 8];
            float4 b1v = *(const float4*)&Bs[k][tx * 8 + 4];
            float av[8] = {a0.x, a0.y, a0.z, a0.w, a1.x, a1.y, a1.z, a1.w};
            float bv[8] = {b0.x, b0.y, b0.z, b0.w, b1v.x, b1v.y, b1v.z, b1v.w};
            #pragma unroll
            for (int i = 0; i < 8; ++i)
                #pragma unroll
                for (int j = 0; j < 8; ++j)
                    acc[i][j] = fmaf(av[i], bv[j], acc[i][j]);
        }
        __syncthreads();
    }
    float qbv[8], vwv[8];
    #pragma unroll
    for (int j = 0; j < 8; ++j) {
        int u = u0 + tx * 8 + j;
        qbv[j] = qb[(n * B_ + b) * U_ + u];
        vwv[j] = Vw[n * U_ + u];
    }
    float wwn = Ww[n];
    #pragma unroll
    for (int i = 0; i < 8; ++i) {
        float p = 0.f;
        #pragma unroll
        for (int j = 0; j < 8; ++j)
            p += vwv[j] * fast_tanh(acc[i][j] + qbv[j]);
        p += __shfl_xor(p, 1);
        p += __shfl_xor(p, 2);
        p += __shfl_xor(p, 4);
        p += __shfl_xor(p, 8);
        if (tx == 0)
            partial[(size_t)blockIdx.y * M_ + rowBase + ty * 8 + i] = wwn * p;
    }
}

// ---------------- tail kernels ----------------
// topk with fused partial-reduction (reads partial directly)
__global__ __launch_bounds__(1024) void topk_kernel(
        const float* __restrict__ partial, int nparts,
        const float* __restrict__ Vb,
        const float* __restrict__ Ww,
        const float* __restrict__ Wb,
        float* __restrict__ out_masked,
        float* __restrict__ w_un) {
    __shared__ float sc[S_];
    __shared__ float srt[S_];
    __shared__ int cnt_gt;
    int b = blockIdx.x;
    int tid = threadIdx.x;
    float cst = Wb[0];
    #pragma unroll
    for (int n2 = 0; n2 < NH; ++n2) cst += Ww[n2] * Vb[n2];
    for (int s = tid; s < S_; s += 1024) {
        float v = cst;
        for (int ct = 0; ct < nparts; ++ct)
            v += partial[(size_t)ct * M_ + b * S_ + s];
        sc[s] = v; srt[s] = v;
    }
    if (tid == 0) cnt_gt = 0;
    __syncthreads();
    for (int k = 2; k <= S_; k <<= 1) {
        for (int j = k >> 1; j >= 1; j >>= 1) {
            int i = ((tid & ~(j - 1)) << 1) | (tid & (j - 1));
            int p = i | j;
            float a = srt[i], c2 = srt[p];
            if (((i & k) == 0) ? (a > c2) : (a < c2)) { srt[i] = c2; srt[p] = a; }
            __syncthreads();
        }
    }
    float T = srt[S_ - TOPK];
    int c = 0;
    for (int s = tid; s < S_; s += 1024) c += (sc[s] > T);
    atomicAdd(&cnt_gt, c);
    __syncthreads();
    int need_eq = TOPK - cnt_gt;
    for (int s = tid; s < S_; s += 1024) {
        float v = sc[s];
        bool sel = (v > T);
        if (v == T) {
            int rank = 0;
            for (int t2 = 0; t2 < s; ++t2) rank += (sc[t2] == T);
            sel = (rank < need_eq);
        }
        float m = sel ? v : 0.f;
        out_masked[b * S_ + s] = m;
        w_un[b * S_ + s] = 1.f / (1.f + __expf(-m));
    }
}

__global__ void norm_w(const float* __restrict__ w_un, float* __restrict__ out_w) {
    int s = blockIdx.x * blockDim.x + threadIdx.x;
    float d = 0.f;
    #pragma unroll
    for (int b = 0; b < B_; ++b) d += w_un[b * S_ + s];
    float inv = 1.f / d;
    #pragma unroll
    for (int b = 0; b < B_; ++b) out_w[b * S_ + s] = w_un[b * S_ + s] * inv;
}

// context partials from 1-level int8 values (v ~= sa*h): 32MB read
__global__ void ctx_partial_h8(const signed char* __restrict__ h8,
                               const float* __restrict__ sa,
                               const float* __restrict__ w,
                               float* __restrict__ pctx) {
    int bb = blockIdx.x;
    int h = blockIdx.y * 256 + threadIdx.x;
    int s0 = blockIdx.z * 256;
    __shared__ float ws[256];
    {
        int s = threadIdx.x;
        ws[s] = w[bb * S_ + s0 + s] * sa[bb * S_ + s0 + s];
    }
    __syncthreads();
    const signed char* hp = h8 + (size_t)(bb * S_ + s0) * H_ + h;
    float acc = 0.f;
    #pragma unroll 4
    for (int s = 0; s < 256; ++s)
        acc += ws[s] * (float)hp[(size_t)s * H_];
    pctx[((size_t)blockIdx.z * B_ + bb) * H_ + h] = acc;
}

__global__ void ctx_partial_f32(const float* __restrict__ values,
                                const float* __restrict__ w,
                                float* __restrict__ pctx) {
    int bb = blockIdx.x;
    int h = blockIdx.y * 256 + threadIdx.x;
    int s0 = blockIdx.z * 256;
    __shared__ float wrow[256];
    wrow[threadIdx.x] = w[bb * S_ + s0 + threadIdx.x];
    __syncthreads();
    const float* vp = values + (size_t)(bb * S_ + s0) * H_ + h;
    float acc = 0.f;
    #pragma unroll 4
    for (int s = 0; s < 256; ++s) acc += wrow[s] * vp[(size_t)s * H_];
    pctx[((size_t)blockIdx.z * B_ + bb) * H_ + h] = acc;
}

__global__ void ctx_reduce(const float* __restrict__ pctx,
                           float* __restrict__ out_ctx) {
    int i = blockIdx.x * blockDim.x + threadIdx.x;
    float s = 0.f;
    #pragma unroll
    for (int z = 0; z < 8; ++z) s += pctx[(size_t)z * B_ * H_ + i];
    out_ctx[i] = s;
}

extern "C" void kernel_launch(void* const* d_in, const int* in_sizes, int n_in,
                              void* d_out, int out_size, void* d_ws, size_t ws_size,
                              hipStream_t stream) {
    const float* query = (const float*)d_in[0];
    const float* values = (const float*)d_in[1];
    const float* W1 = (const float*)d_in[2];
    const float* b1 = (const float*)d_in[3];
    const float* W2 = (const float*)d_in[4];
    const float* b2 = (const float*)d_in[5];
    const float* Vw = (const float*)d_in[6];
    const float* Vb = (const float*)d_in[7];
    const float* Ww = (const float*)d_in[8];
    const float* Wb = (const float*)d_in[9];

    float* ws = (float*)d_ws;
    float* qb      = ws;                     // 65536
    float* qbp     = qb + 65536;             // 1048576 (16 x 65536)
    float* partial = qbp + 1048576;          // 1048576 (32 x 32768)
    float* w_un    = partial + 1048576;      // 32768
    float* pctx    = w_un + 32768;           // 131072
    float* sa      = pctx + 131072;          // 32768
    float* colmax  = sa + 32768;             // 4096
    signed char* Ah8 = (signed char*)(colmax + 4096);  // 32 MB
    signed char* Bh8 = Ah8 + (size_t)M_ * H_;          // 4 MB
    size_t needed = (size_t)((char*)(Bh8 + (size_t)NC * H_) - (char*)d_ws);

    float* out_ctx    = (float*)d_out;       // 16384
    float* out_w      = out_ctx + 16384;     // 32768
    float* out_masked = out_w + 32768;       // 32768

    qbp_kernel<<<dim3(NH, 16), 512, 0, stream>>>(query, W2, qbp);
    qb_reduce<<<dim3(256), 256, 0, stream>>>(qbp, b1, b2, qb);
    if (ws_size >= needed) {
        cvtA<<<dim3(8192), 256, 0, stream>>>(values, Ah8, sa);
        hipMemsetAsync(colmax, 0, NC * sizeof(float), stream);
        colmax_kernel<<<dim3(NH, 16), 512, 0, stream>>>(W1, colmax);
        cvtB8<<<dim3(NH, 16, 8), 256, 0, stream>>>(W1, colmax, Bh8);
        gemm8i<<<dim3(2048), 512, 0, stream>>>(Ah8, Bh8, sa, colmax,
                                               qb, Vw, Ww, partial);
        topk_kernel<<<16, 1024, 0, stream>>>(partial, 16, Vb, Ww, Wb, out_masked, w_un);
        norm_w<<<8, 256, 0, stream>>>(w_un, out_w);
        ctx_partial_h8<<<dim3(16, 4, 8), 256, 0, stream>>>(Ah8, sa, out_w, pctx);
    } else {
        gemm_score<<<dim3(256, 32), 256, 0, stream>>>(values, W1, qb, Vw, Ww, partial);
        topk_kernel<<<16, 1024, 0, stream>>>(partial, 32, Vb, Ww, Wb, out_masked, w_un);
        norm_w<<<8, 256, 0, stream>>>(w_un, out_w);
        ctx_partial_f32<<<dim3(16, 4, 8), 256, 0, stream>>>(values, out_w, pctx);
    }
    ctx_reduce<<<64, 256, 0, stream>>>(pctx, out_ctx);
}